// Round 7
// baseline (425.114 us; speedup 1.0000x reference)
//
#include <hip/hip_runtime.h>
#include <hip/hip_fp16.h>

// Problem constants: B=16, S=512, HID=512, NH=8, DK=64, TH=32, TE=16, scale=1/8

typedef __attribute__((ext_vector_type(8))) __bf16 bf16x8;
typedef __attribute__((ext_vector_type(8))) _Float16 f16x8;
typedef __attribute__((ext_vector_type(4))) float f32x4;

static __device__ __forceinline__ unsigned short f2bf(float f) {
  unsigned u = __float_as_uint(f);
  unsigned r = (u + 0x7fffu + ((u >> 16) & 1u)) >> 16;   // RNE
  return (unsigned short)r;
}
static __device__ __forceinline__ unsigned short f2h(float f) {
  _Float16 h = (_Float16)f;
  return __builtin_bit_cast(unsigned short, h);
}
static __device__ __forceinline__ float h2f(unsigned short u) {
  _Float16 h = __builtin_bit_cast(_Float16, u);
  return (float)h;
}
static __device__ __forceinline__ f16x8 ldembB(const float* __restrict__ T,
                                               int row, int off) {
  float4 a = *reinterpret_cast<const float4*>(&T[(size_t)row * 512 + off]);
  float4 b = *reinterpret_cast<const float4*>(&T[(size_t)row * 512 + off + 4]);
  f16x8 r;
  r[0] = (_Float16)a.x; r[1] = (_Float16)a.y; r[2] = (_Float16)a.z; r[3] = (_Float16)a.w;
  r[4] = (_Float16)b.x; r[5] = (_Float16)b.y; r[6] = (_Float16)b.z; r[7] = (_Float16)b.w;
  return r;
}

// ---------------------------------------------------------------------------
// K1 prologue: blocks 0..767 = fused Q/K/V projection GEMMs (f32 in, f16 out,
// f32->bf16 folded into staging, register prefetch); blocks 768..1023 =
// pack dist|edge<<8 into uint16 (grid-stride). One launch, independent parts.
// ---------------------------------------------------------------------------
__global__ __launch_bounds__(256) void prologue(
    const float* __restrict__ qf, const float* __restrict__ kf,
    const float* __restrict__ vf,
    const float* __restrict__ Wq, const float* __restrict__ Wk,
    const float* __restrict__ Wv,
    const float* __restrict__ bq, const float* __restrict__ bk,
    const float* __restrict__ bv,
    unsigned short* __restrict__ qh16, unsigned short* __restrict__ kh16,
    unsigned short* __restrict__ vht,
    const int* __restrict__ dist, const int* __restrict__ edge,
    unsigned short* __restrict__ de16)
{
  __shared__ unsigned short As[128][40];
  __shared__ unsigned short Bs[128][40];
  const int bid = blockIdx.x;
  const int tid = threadIdx.x;

  if (bid >= 768) {                    // ---- pack_de part (memory-bound)
    const int pb = bid - 768;
    #pragma unroll
    for (int rep = 0; rep < 8; rep++) {
      size_t base = ((size_t)(rep * 65536 + pb * 256 + tid)) * 8;
      int4 d0 = *reinterpret_cast<const int4*>(&dist[base]);
      int4 d1 = *reinterpret_cast<const int4*>(&dist[base + 4]);
      int4 e0 = *reinterpret_cast<const int4*>(&edge[base]);
      int4 e1 = *reinterpret_cast<const int4*>(&edge[base + 4]);
      ushort4 u0, u1;
      u0.x = (unsigned short)(d0.x | (e0.x << 8));
      u0.y = (unsigned short)(d0.y | (e0.y << 8));
      u0.z = (unsigned short)(d0.z | (e0.z << 8));
      u0.w = (unsigned short)(d0.w | (e0.w << 8));
      u1.x = (unsigned short)(d1.x | (e1.x << 8));
      u1.y = (unsigned short)(d1.y | (e1.y << 8));
      u1.z = (unsigned short)(d1.z | (e1.z << 8));
      u1.w = (unsigned short)(d1.w | (e1.w << 8));
      *reinterpret_cast<ushort4*>(&de16[base]) = u0;
      *reinterpret_cast<ushort4*>(&de16[base + 4]) = u1;
    }
    return;
  }

  // ---- projection GEMM part
  const int z = bid >> 8;              // 0=q, 1=k, 2=v
  const int xy = bid & 255;
  const int m0 = (xy & 63) * 128;
  const int n0 = (xy >> 6) * 128;
  const float* X = (z == 0) ? qf : (z == 1) ? kf : vf;
  const float* W = (z == 0) ? Wq : (z == 1) ? Wk : Wv;
  const float* bias = (z == 0) ? bq : (z == 1) ? bk : bv;
  unsigned short* Y = (z == 0) ? qh16 : (z == 1) ? kh16 : vht;

  const int lane = tid & 63;
  const int w = tid >> 6;
  const int wr = w >> 1, wc = w & 1;
  const int l15 = lane & 15, quad = lane >> 4;

  const int srow = tid & 127;
  const float* srcrow = (tid < 128) ? &X[(size_t)(m0 + srow) * 512]
                                    : &W[(size_t)(n0 + srow) * 512];
  unsigned short* dstrow = (tid < 128) ? As[srow] : Bs[srow];

  f32x4 acc[4][4];
  #pragma unroll
  for (int i = 0; i < 4; i++)
    #pragma unroll
    for (int j = 0; j < 4; j++) acc[i][j] = (f32x4){0.f, 0.f, 0.f, 0.f};

  float4 pf[8];
  #pragma unroll
  for (int u = 0; u < 8; u++)
    pf[u] = *reinterpret_cast<const float4*>(&srcrow[u * 4]);

  for (int k0 = 0; k0 < 512; k0 += 32) {
    __syncthreads();
    #pragma unroll
    for (int u = 0; u < 4; u++) {
      float4 a = pf[2*u], b2 = pf[2*u + 1];
      ushort4 lo, hi;
      lo.x = f2bf(a.x);  lo.y = f2bf(a.y);  lo.z = f2bf(a.z);  lo.w = f2bf(a.w);
      hi.x = f2bf(b2.x); hi.y = f2bf(b2.y); hi.z = f2bf(b2.z); hi.w = f2bf(b2.w);
      *reinterpret_cast<ushort4*>(&dstrow[u * 8]) = lo;
      *reinterpret_cast<ushort4*>(&dstrow[u * 8 + 4]) = hi;
    }
    __syncthreads();
    if (k0 < 480) {
      #pragma unroll
      for (int u = 0; u < 8; u++)
        pf[u] = *reinterpret_cast<const float4*>(&srcrow[k0 + 32 + u * 4]);
    }
    bf16x8 af[4], bfr[4];
    #pragma unroll
    for (int mt = 0; mt < 4; mt++)
      af[mt] = *reinterpret_cast<const bf16x8*>(&As[wr * 64 + mt * 16 + l15][quad * 8]);
    #pragma unroll
    for (int nt = 0; nt < 4; nt++)
      bfr[nt] = *reinterpret_cast<const bf16x8*>(&Bs[wc * 64 + nt * 16 + l15][quad * 8]);
    #pragma unroll
    for (int mt = 0; mt < 4; mt++)
      #pragma unroll
      for (int nt = 0; nt < 4; nt++)
        acc[mt][nt] = __builtin_amdgcn_mfma_f32_16x16x32_bf16(
            af[mt], bfr[nt], acc[mt][nt], 0, 0, 0);
  }

  float bn[4];
  #pragma unroll
  for (int nt = 0; nt < 4; nt++)
    bn[nt] = bias[n0 + wc * 64 + nt * 16 + l15];

  if (z < 2) {
    #pragma unroll
    for (int mt = 0; mt < 4; mt++) {
      #pragma unroll
      for (int r = 0; r < 4; r++) {
        int m = m0 + wr * 64 + mt * 16 + quad * 4 + r;
        int bb = m >> 9, s = m & 511;
        #pragma unroll
        for (int nt = 0; nt < 4; nt++) {
          int n = n0 + wc * 64 + nt * 16 + l15;
          int h = n >> 6, d = n & 63;
          Y[(((size_t)(bb * 8 + h) * 512) + s) * 64 + d] = f2h(acc[mt][nt][r] + bn[nt]);
        }
      }
    }
  } else {
    #pragma unroll
    for (int mt = 0; mt < 4; mt++) {
      #pragma unroll
      for (int r = 0; r < 4; r++) {
        int m = m0 + wr * 64 + mt * 16 + quad * 4 + r;
        int bb = m >> 9, s = m & 511;
        #pragma unroll
        for (int nt = 0; nt < 4; nt++) {
          int n = n0 + wc * 64 + nt * 16 + l15;
          int h = n >> 6, d = n & 63;
          size_t bh = (size_t)(bb * 8 + h);
          Y[(bh * 16 + (s >> 5)) * 2048 + d * 32 + (s & 31)] = f2h(acc[mt][nt][r] + bn[nt]);
        }
      }
    }
  }
}

// ---------------------------------------------------------------------------
// Fused MFMA attention v11: table GEMMs folded in (table_mfma kernel deleted).
//  - Phase A: Aq (qh.qhe^T) and QKe (qh.qee^T + kh.kee^T) via MFMA -> LDS,
//    reusing the already-loaded bq0/bq1 as A-fragments.
//  - In-loop: Bkh chunk (kh.khe^T) via 4 MFMAs/tile reusing kf0/kf1; the
//    C-layout (col=l15, row=quad*4+reg) puts row jbase+rr in MY quad ->
//    gather bkh[jbase+rr][t_] = 2x __shfl + select. bkhw LDS deleted.
//  - XCD remap: blk%8 = b&7 (was h) -> de16[b] slab + all tiles of a bh on
//    ONE XCD; measured 63 MB FETCH was ~de16 re-fetched per XCD (8x).
// LDS 15,872 B. Barrier-free main loop + register binning unchanged (r5 win).
// ---------------------------------------------------------------------------
__global__ __launch_bounds__(256, 4) void attn_mfma(
    const unsigned short* __restrict__ qh16, const unsigned short* __restrict__ kh16,
    const unsigned short* __restrict__ vht,
    const float* __restrict__ qhe, const float* __restrict__ qee,
    const float* __restrict__ khe, const float* __restrict__ kee,
    const float* __restrict__ vhe, const float* __restrict__ vee,
    const unsigned short* __restrict__ de16,
    unsigned short* __restrict__ outp_bf)
{
  const int blk = blockIdx.x;
  const int rt = blk >> 7;
  const int low = blk & 127;
  const int bh = ((low & 15) << 3) | (low >> 4);   // blk%8 == b&7 (bijective)
  const int b = bh >> 3, h = bh & 7;
  const int i0 = rt * 64;
  const int tid = threadIdx.x;
  const int w = tid >> 6;
  const int lane = tid & 63;
  const int l15 = lane & 15, quad = lane >> 4;
  const int bhS = bh * 512;
  const int iL = w * 16 + l15;         // this lane's block-local i-row

  __shared__ union {
    struct {
      float AqF[64][34];               // 8704 B (loop, read-only)
      unsigned short QKes[64][16];     // 2048 B (loop, read-only)
    } a;
    unsigned short embT[64][72];       // 9216 B (epilogue only)
  } U;                                 // 10752 B
  __shared__ unsigned short Pp[4][16][40];    // 5120 B per-wave P tile
  // total 15,872 B

  const int hoff = h * 64;

  // Q and K fragments for this lane's i-row (bq* reused as Aq A-frags)
  f16x8 bq0 = *reinterpret_cast<const f16x8*>(&qh16[(size_t)(bhS + i0 + iL)*64 + quad*8]);
  f16x8 bq1 = *reinterpret_cast<const f16x8*>(&qh16[(size_t)(bhS + i0 + iL)*64 + 32 + quad*8]);
  f16x8 ak0 = *reinterpret_cast<const f16x8*>(&kh16[(size_t)(bhS + i0 + iL)*64 + quad*8]);
  f16x8 ak1 = *reinterpret_cast<const f16x8*>(&kh16[(size_t)(bhS + i0 + iL)*64 + 32 + quad*8]);

  // emb table B-fragments (f32 -> f16); kheB stays live for the main loop
  f16x8 kheB[2][2], qheB[2][2], qeeB[2], keeB[2];
  #pragma unroll
  for (int nt = 0; nt < 2; nt++)
    #pragma unroll
    for (int kk = 0; kk < 2; kk++) {
      qheB[nt][kk] = ldembB(qhe, nt * 16 + l15, hoff + kk * 32 + quad * 8);
      kheB[nt][kk] = ldembB(khe, nt * 16 + l15, hoff + kk * 32 + quad * 8);
    }
  #pragma unroll
  for (int kk = 0; kk < 2; kk++) {
    qeeB[kk] = ldembB(qee, l15, hoff + kk * 32 + quad * 8);
    keeB[kk] = ldembB(kee, l15, hoff + kk * 32 + quad * 8);
  }

  // Phase A table MFMAs: Aq[i][t] (2 n-tiles) and QKe[i][e]
  {
    f32x4 aacc[2]; f32x4 eacc = (f32x4){0.f,0.f,0.f,0.f};
    #pragma unroll
    for (int nt = 0; nt < 2; nt++) {
      aacc[nt] = (f32x4){0.f,0.f,0.f,0.f};
      aacc[nt] = __builtin_amdgcn_mfma_f32_16x16x32_f16(bq0, qheB[nt][0], aacc[nt], 0, 0, 0);
      aacc[nt] = __builtin_amdgcn_mfma_f32_16x16x32_f16(bq1, qheB[nt][1], aacc[nt], 0, 0, 0);
    }
    eacc = __builtin_amdgcn_mfma_f32_16x16x32_f16(bq0, qeeB[0], eacc, 0, 0, 0);
    eacc = __builtin_amdgcn_mfma_f32_16x16x32_f16(bq1, qeeB[1], eacc, 0, 0, 0);
    eacc = __builtin_amdgcn_mfma_f32_16x16x32_f16(ak0, keeB[0], eacc, 0, 0, 0);
    eacc = __builtin_amdgcn_mfma_f32_16x16x32_f16(ak1, keeB[1], eacc, 0, 0, 0);
    // C layout: row (=i within wave's 16) = quad*4+r, col (=t/e) = l15
    #pragma unroll
    for (int r = 0; r < 4; r++) {
      #pragma unroll
      for (int nt = 0; nt < 2; nt++)
        U.a.AqF[w*16 + quad*4 + r][nt*16 + l15] = aacc[nt][r];
      U.a.QKes[w*16 + quad*4 + r][l15] = f2h(eacc[r]);
    }
  }
  __syncthreads();   // the ONLY pre-loop barrier (AqF/QKes ready)

  const size_t deBase = ((size_t)b*512 + i0 + iL) * 512;  // lane's de16 row

  f32x4 Oacc[4];
  #pragma unroll
  for (int nt = 0; nt < 4; nt++) Oacc[nt] = (f32x4){0.f,0.f,0.f,0.f};
  float sum = 0.f;

  // per-lane register mass bins for row iL (this quad's j-slice)
  float hb[32], eb[16];
  #pragma unroll
  for (int t = 0; t < 32; t++) hb[t] = 0.f;
  #pragma unroll
  for (int t = 0; t < 16; t++) eb[t] = 0.f;

  for (int jc = 0; jc < 16; jc++) {
    const int j0 = jc * 32;

    // per-lane dist/edge (independent global loads; TLP hides latency)
    ushort4 deA = *reinterpret_cast<const ushort4*>(&de16[deBase + j0 + quad*4]);
    ushort4 deB = *reinterpret_cast<const ushort4*>(&de16[deBase + j0 + 16 + quad*4]);

    // QK swapped: C[j = quad*4+r (+tile*16), i = l15]; K frags from global.
    // Bkh for this tile computed in-register from the same kf0/kf1.
    #pragma unroll
    for (int tile = 0; tile < 2; tile++) {
      const size_t krow = (size_t)(bhS + j0 + tile*16 + l15) * 64;
      f16x8 kf0 = *reinterpret_cast<const f16x8*>(&kh16[krow + quad*8]);
      f16x8 kf1 = *reinterpret_cast<const f16x8*>(&kh16[krow + 32 + quad*8]);
      f32x4 sacc = (f32x4){0.f,0.f,0.f,0.f};
      sacc = __builtin_amdgcn_mfma_f32_16x16x32_f16(kf0, bq0, sacc, 0, 0, 0);
      sacc = __builtin_amdgcn_mfma_f32_16x16x32_f16(kf1, bq1, sacc, 0, 0, 0);
      // bkh[tile*16+quad*4+r][t]: t<16 in bk0 (col l15), t>=16 in bk1
      f32x4 bk0 = (f32x4){0.f,0.f,0.f,0.f};
      f32x4 bk1 = (f32x4){0.f,0.f,0.f,0.f};
      bk0 = __builtin_amdgcn_mfma_f32_16x16x32_f16(kf0, kheB[0][0], bk0, 0, 0, 0);
      bk0 = __builtin_amdgcn_mfma_f32_16x16x32_f16(kf1, kheB[0][1], bk0, 0, 0, 0);
      bk1 = __builtin_amdgcn_mfma_f32_16x16x32_f16(kf0, kheB[1][0], bk1, 0, 0, 0);
      bk1 = __builtin_amdgcn_mfma_f32_16x16x32_f16(kf1, kheB[1][1], bk1, 0, 0, 0);
      const ushort4 de = tile ? deB : deA;
      ushort4 pw;

#define SCALAR_R(rr, ue, pdst)                                                \
      {                                                                       \
        const unsigned u_ = (ue);                                             \
        const int t_ = u_ & 0xFF, e_ = u_ >> 8;                               \
        const int sidx = quad * 16 + (t_ & 15);                               \
        float s0 = __shfl(bk0[rr], sidx);                                     \
        float s1 = __shfl(bk1[rr], sidx);                                     \
        float bkhv = (t_ < 16) ? s0 : s1;                                     \
        float bias_ = U.a.AqF[iL][t_] + bkhv + h2f(U.a.QKes[iL][e_]);         \
        float s_ = (sacc[rr] + bias_) * 0.125f;                               \
        float p_ = __expf(fminf(s_, 10.f));                                   \
        sum += p_;                                                            \
        _Pragma("unroll")                                                     \
        for (int t = 0; t < 32; t++) hb[t] += (t == t_) ? p_ : 0.f;           \
        _Pragma("unroll")                                                     \
        for (int t = 0; t < 16; t++) eb[t] += (t == e_) ? p_ : 0.f;           \
        pdst = f2h(p_);                                                       \
      }
      SCALAR_R(0, de.x, pw.x)
      SCALAR_R(1, de.y, pw.y)
      SCALAR_R(2, de.z, pw.z)
      SCALAR_R(3, de.w, pw.w)
#undef SCALAR_R

      // one aligned b64 write: P[i=l15][j = jbase..jbase+3]
      *reinterpret_cast<ushort4*>(&Pp[w][l15][tile*16 + quad*4]) = pw;
    }

    // PV via MFMA (K=32 over this chunk); A = P (wave-private), B = V^T global
    {
      f16x8 ap = *reinterpret_cast<const f16x8*>(&Pp[w][l15][quad*8]);
      const size_t vbase = ((size_t)bh*16 + jc)*2048;
      #pragma unroll
      for (int nt = 0; nt < 4; nt++) {
        f16x8 bv = *reinterpret_cast<const f16x8*>(
            &vht[vbase + (nt*16 + l15)*32 + quad*8]);
        Oacc[nt] = __builtin_amdgcn_mfma_f32_16x16x32_f16(ap, bv, Oacc[nt], 0, 0, 0);
      }
    }
    // NO barrier: everything in this loop is wave-private or read-only.
  }

  // cross-quad reduce: combine the 4 quads' j-slices of row iL.
  sum += __shfl_xor(sum, 16);
  sum += __shfl_xor(sum, 32);
  #pragma unroll
  for (int t = 0; t < 32; t++) {
    hb[t] += __shfl_xor(hb[t], 16);
    hb[t] += __shfl_xor(hb[t], 32);
  }
  #pragma unroll
  for (int t = 0; t < 16; t++) {
    eb[t] += __shfl_xor(eb[t], 16);
    eb[t] += __shfl_xor(eb[t], 32);
  }
  float ri[4];
  #pragma unroll
  for (int r = 0; r < 4; r++) ri[r] = 1.0f / __shfl(sum, quad*4 + r);

  __syncthreads();   // all waves done reading U.a before embT overlays it

  // stage embT [d][k]: k<32 -> vhe, 32..47 -> vee, else 0
  {
    int d = tid & 63, ks0 = (tid >> 6) * 16;
    #pragma unroll
    for (int g = 0; g < 4; g++) {
      ushort4 u;
      #pragma unroll
      for (int kk = 0; kk < 4; kk++) {
        int k = ks0 + g*4 + kk;
        float val = (k < 32) ? vhe[k*512 + h*64 + d]
                  : (k < 48) ? vee[(k-32)*512 + h*64 + d] : 0.f;
        ((unsigned short*)&u)[kk] = f2h(val);
      }
      *reinterpret_cast<ushort4*>(&U.embT[d][ks0 + g*4]) = u;
    }
  }
  __syncthreads();   // embT visible to all waves

  // mass . emb via MFMA; A-frags built from register bins (static selects)
  {
    f16x8 am0, am1;
    #pragma unroll
    for (int j = 0; j < 8; j++) {
      float hv = (quad == 0) ? hb[j]
               : (quad == 1) ? hb[8 + j]
               : (quad == 2) ? hb[16 + j] : hb[24 + j];
      am0[j] = (_Float16)hv;
      float ve = (quad == 0) ? eb[j]
               : (quad == 1) ? eb[8 + j] : 0.f;
      am1[j] = (_Float16)ve;
    }
    #pragma unroll
    for (int nt = 0; nt < 4; nt++) {
      f16x8 be0 = *reinterpret_cast<const f16x8*>(&U.embT[nt*16 + l15][quad*8]);
      f16x8 be1 = *reinterpret_cast<const f16x8*>(&U.embT[nt*16 + l15][32 + quad*8]);
      Oacc[nt] = __builtin_amdgcn_mfma_f32_16x16x32_f16(am0, be0, Oacc[nt], 0, 0, 0);
      Oacc[nt] = __builtin_amdgcn_mfma_f32_16x16x32_f16(am1, be1, Oacc[nt], 0, 0, 0);
    }
  }

  // normalize + store bf16
  #pragma unroll
  for (int nt = 0; nt < 4; nt++) {
    #pragma unroll
    for (int r = 0; r < 4; r++) {
      int srow = i0 + w*16 + quad*4 + r;
      outp_bf[(size_t)(b*512 + srow)*512 + h*64 + nt*16 + l15] = f2bf(Oacc[nt][r] * ri[r]);
    }
  }
}

// ---------------------------------------------------------------------------
// Output proj: X = bf16 (attn output), W = f32 Wo converted in staging.
// ---------------------------------------------------------------------------
__global__ __launch_bounds__(256) void out_mfma(
    const unsigned short* __restrict__ X, const float* __restrict__ Wof,
    const float* __restrict__ bias, float* __restrict__ Y)
{
  __shared__ unsigned short As[128][40];
  __shared__ unsigned short Bs[128][40];
  const int tid = threadIdx.x;
  const int m0 = blockIdx.x * 128;
  const int n0 = blockIdx.y * 128;
  const int lane = tid & 63;
  const int w = tid >> 6;
  const int wr = w >> 1, wc = w & 1;
  const int l15 = lane & 15, quad = lane >> 4;

  const int srow = tid & 127;
  const bool isA = (tid < 128);
  const unsigned short* srcA = &X[(size_t)(m0 + srow) * 512];
  const float* srcB = &Wof[(size_t)(n0 + srow) * 512];
  unsigned short* dstrow = isA ? As[srow] : Bs[srow];

  f32x4 acc[4][4];
  #pragma unroll
  for (int i = 0; i < 4; i++)
    #pragma unroll
    for (int j = 0; j < 4; j++) acc[i][j] = (f32x4){0.f, 0.f, 0.f, 0.f};

  uint4 pa[4]; float4 pb[8];
  if (isA) {
    #pragma unroll
    for (int u = 0; u < 4; u++)
      pa[u] = *reinterpret_cast<const uint4*>(&srcA[u * 8]);
  } else {
    #pragma unroll
    for (int u = 0; u < 8; u++)
      pb[u] = *reinterpret_cast<const float4*>(&srcB[u * 4]);
  }

  for (int k0 = 0; k0 < 512; k0 += 32) {
    __syncthreads();
    if (isA) {
      #pragma unroll
      for (int u = 0; u < 4; u++)
        *reinterpret_cast<uint4*>(&dstrow[u * 8]) = pa[u];
    } else {
      #pragma unroll
      for (int u = 0; u < 4; u++) {
        float4 a = pb[2*u], b2 = pb[2*u + 1];
        ushort4 lo, hi;
        lo.x = f2bf(a.x);  lo.y = f2bf(a.y);  lo.z = f2bf(a.z);  lo.w = f2bf(a.w);
        hi.x = f2bf(b2.x); hi.y = f2bf(b2.y); hi.z = f2bf(b2.z); hi.w = f2bf(b2.w);
        *reinterpret_cast<ushort4*>(&dstrow[u * 8]) = lo;
        *reinterpret_cast<ushort4*>(&dstrow[u * 8 + 4]) = hi;
      }
    }
    __syncthreads();
    if (k0 < 480) {
      if (isA) {
        #pragma unroll
        for (int u = 0; u < 4; u++)
          pa[u] = *reinterpret_cast<const uint4*>(&srcA[k0 + 32 + u * 8]);
      } else {
        #pragma unroll
        for (int u = 0; u < 8; u++)
          pb[u] = *reinterpret_cast<const float4*>(&srcB[k0 + 32 + u * 4]);
      }
    }
    bf16x8 af[4], bfr[4];
    #pragma unroll
    for (int mt = 0; mt < 4; mt++)
      af[mt] = *reinterpret_cast<const bf16x8*>(&As[wr * 64 + mt * 16 + l15][quad * 8]);
    #pragma unroll
    for (int nt = 0; nt < 4; nt++)
      bfr[nt] = *reinterpret_cast<const bf16x8*>(&Bs[wc * 64 + nt * 16 + l15][quad * 8]);
    #pragma unroll
    for (int mt = 0; mt < 4; mt++)
      #pragma unroll
      for (int nt = 0; nt < 4; nt++)
        acc[mt][nt] = __builtin_amdgcn_mfma_f32_16x16x32_bf16(
            af[mt], bfr[nt], acc[mt][nt], 0, 0, 0);
  }

  float bn[4];
  #pragma unroll
  for (int nt = 0; nt < 4; nt++)
    bn[nt] = bias[n0 + wc * 64 + nt * 16 + l15];
  #pragma unroll
  for (int mt = 0; mt < 4; mt++) {
    #pragma unroll
    for (int r = 0; r < 4; r++) {
      int m = m0 + wr * 64 + mt * 16 + quad * 4 + r;
      #pragma unroll
      for (int nt = 0; nt < 4; nt++) {
        int n = n0 + wc * 64 + nt * 16 + l15;
        Y[(size_t)m * 512 + n] = acc[mt][nt][r] + bn[nt];
      }
    }
  }
}

// ---------------------------------------------------------------------------
extern "C" void kernel_launch(void* const* d_in, const int* in_sizes, int n_in,
                              void* d_out, int out_size, void* d_ws, size_t ws_size,
                              hipStream_t stream) {
  (void)in_sizes; (void)n_in; (void)out_size; (void)ws_size;
  const float* q    = (const float*)d_in[0];
  const float* k    = (const float*)d_in[1];
  const float* v    = (const float*)d_in[2];
  const float* qhe  = (const float*)d_in[3];
  const float* qee  = (const float*)d_in[4];
  const float* khe  = (const float*)d_in[5];
  const float* kee  = (const float*)d_in[6];
  const float* vhe  = (const float*)d_in[7];
  const float* vee  = (const float*)d_in[8];
  const int*  dist  = (const int*)d_in[9];
  const int*  edge  = (const int*)d_in[10];
  const float* Wq = (const float*)d_in[11];
  const float* bq = (const float*)d_in[12];
  const float* Wk = (const float*)d_in[13];
  const float* bk = (const float*)d_in[14];
  const float* Wv = (const float*)d_in[15];
  const float* bv = (const float*)d_in[16];
  const float* Wo = (const float*)d_in[17];
  const float* bo = (const float*)d_in[18];

  // ---- workspace layout (bytes) ----
  char* ws = (char*)d_ws;
  unsigned short* qh16  = (unsigned short*)(ws + 0);          // 8,388,608 B
  unsigned short* kh16  = (unsigned short*)(ws + 8388608);    // 8,388,608
  unsigned short* vht   = (unsigned short*)(ws + 16777216);   // 8,388,608
  unsigned short* de16  = (unsigned short*)(ws + 46137344);   // 8,388,608 packed dist|edge
  unsigned short* outp_bf = (unsigned short*)(ws + 71303168); // 8,388,608

  dim3 blk(256);
  hipLaunchKernelGGL(prologue, dim3(1024), blk, 0, stream,
                     q, k, v, Wq, Wk, Wv, bq, bk, bv, qh16, kh16, vht,
                     dist, edge, de16);
  hipLaunchKernelGGL(attn_mfma, dim3(1024), blk, 0, stream,
                     qh16, kh16, vht, qhe, qee, khe, kee, vhe, vee, de16, outp_bf);
  hipLaunchKernelGGL(out_mfma, dim3(64, 4), blk, 0, stream,
                     outp_bf, Wo, bo, (float*)d_out);
}

// Round 8
// 418.543 us; speedup vs baseline: 1.0157x; 1.0157x over previous
//
#include <hip/hip_runtime.h>
#include <hip/hip_fp16.h>

// Problem constants: B=16, S=512, HID=512, NH=8, DK=64, TH=32, TE=16, scale=1/8

typedef __attribute__((ext_vector_type(8))) __bf16 bf16x8;
typedef __attribute__((ext_vector_type(8))) _Float16 f16x8;
typedef __attribute__((ext_vector_type(4))) float f32x4;

static __device__ __forceinline__ unsigned short f2bf(float f) {
  unsigned u = __float_as_uint(f);
  unsigned r = (u + 0x7fffu + ((u >> 16) & 1u)) >> 16;   // RNE
  return (unsigned short)r;
}
static __device__ __forceinline__ unsigned short f2h(float f) {
  _Float16 h = (_Float16)f;
  return __builtin_bit_cast(unsigned short, h);
}
static __device__ __forceinline__ float h2f(unsigned short u) {
  _Float16 h = __builtin_bit_cast(_Float16, u);
  return (float)h;
}
static __device__ __forceinline__ f16x8 ldembB(const float* __restrict__ T,
                                               int row, int off) {
  float4 a = *reinterpret_cast<const float4*>(&T[(size_t)row * 512 + off]);
  float4 b = *reinterpret_cast<const float4*>(&T[(size_t)row * 512 + off + 4]);
  f16x8 r;
  r[0] = (_Float16)a.x; r[1] = (_Float16)a.y; r[2] = (_Float16)a.z; r[3] = (_Float16)a.w;
  r[4] = (_Float16)b.x; r[5] = (_Float16)b.y; r[6] = (_Float16)b.z; r[7] = (_Float16)b.w;
  return r;
}

// ---------------------------------------------------------------------------
// K1 prologue: blocks 0..767 = fused Q/K/V projection GEMMs (f32 in, f16 out,
// f32->bf16 folded into staging, register prefetch); blocks 768..1023 =
// pack dist|edge<<8 into uint16 (grid-stride). One launch, independent parts.
// ---------------------------------------------------------------------------
__global__ __launch_bounds__(256) void prologue(
    const float* __restrict__ qf, const float* __restrict__ kf,
    const float* __restrict__ vf,
    const float* __restrict__ Wq, const float* __restrict__ Wk,
    const float* __restrict__ Wv,
    const float* __restrict__ bq, const float* __restrict__ bk,
    const float* __restrict__ bv,
    unsigned short* __restrict__ qh16, unsigned short* __restrict__ kh16,
    unsigned short* __restrict__ vht,
    const int* __restrict__ dist, const int* __restrict__ edge,
    unsigned short* __restrict__ de16)
{
  __shared__ unsigned short As[128][40];
  __shared__ unsigned short Bs[128][40];
  const int bid = blockIdx.x;
  const int tid = threadIdx.x;

  if (bid >= 768) {                    // ---- pack_de part (memory-bound)
    const int pb = bid - 768;
    #pragma unroll
    for (int rep = 0; rep < 8; rep++) {
      size_t base = ((size_t)(rep * 65536 + pb * 256 + tid)) * 8;
      int4 d0 = *reinterpret_cast<const int4*>(&dist[base]);
      int4 d1 = *reinterpret_cast<const int4*>(&dist[base + 4]);
      int4 e0 = *reinterpret_cast<const int4*>(&edge[base]);
      int4 e1 = *reinterpret_cast<const int4*>(&edge[base + 4]);
      ushort4 u0, u1;
      u0.x = (unsigned short)(d0.x | (e0.x << 8));
      u0.y = (unsigned short)(d0.y | (e0.y << 8));
      u0.z = (unsigned short)(d0.z | (e0.z << 8));
      u0.w = (unsigned short)(d0.w | (e0.w << 8));
      u1.x = (unsigned short)(d1.x | (e1.x << 8));
      u1.y = (unsigned short)(d1.y | (e1.y << 8));
      u1.z = (unsigned short)(d1.z | (e1.z << 8));
      u1.w = (unsigned short)(d1.w | (e1.w << 8));
      *reinterpret_cast<ushort4*>(&de16[base]) = u0;
      *reinterpret_cast<ushort4*>(&de16[base + 4]) = u1;
    }
    return;
  }

  // ---- projection GEMM part
  const int z = bid >> 8;              // 0=q, 1=k, 2=v
  const int xy = bid & 255;
  const int m0 = (xy & 63) * 128;
  const int n0 = (xy >> 6) * 128;
  const float* X = (z == 0) ? qf : (z == 1) ? kf : vf;
  const float* W = (z == 0) ? Wq : (z == 1) ? Wk : Wv;
  const float* bias = (z == 0) ? bq : (z == 1) ? bk : bv;
  unsigned short* Y = (z == 0) ? qh16 : (z == 1) ? kh16 : vht;

  const int lane = tid & 63;
  const int w = tid >> 6;
  const int wr = w >> 1, wc = w & 1;
  const int l15 = lane & 15, quad = lane >> 4;

  const int srow = tid & 127;
  const float* srcrow = (tid < 128) ? &X[(size_t)(m0 + srow) * 512]
                                    : &W[(size_t)(n0 + srow) * 512];
  unsigned short* dstrow = (tid < 128) ? As[srow] : Bs[srow];

  f32x4 acc[4][4];
  #pragma unroll
  for (int i = 0; i < 4; i++)
    #pragma unroll
    for (int j = 0; j < 4; j++) acc[i][j] = (f32x4){0.f, 0.f, 0.f, 0.f};

  float4 pf[8];
  #pragma unroll
  for (int u = 0; u < 8; u++)
    pf[u] = *reinterpret_cast<const float4*>(&srcrow[u * 4]);

  for (int k0 = 0; k0 < 512; k0 += 32) {
    __syncthreads();
    #pragma unroll
    for (int u = 0; u < 4; u++) {
      float4 a = pf[2*u], b2 = pf[2*u + 1];
      ushort4 lo, hi;
      lo.x = f2bf(a.x);  lo.y = f2bf(a.y);  lo.z = f2bf(a.z);  lo.w = f2bf(a.w);
      hi.x = f2bf(b2.x); hi.y = f2bf(b2.y); hi.z = f2bf(b2.z); hi.w = f2bf(b2.w);
      *reinterpret_cast<ushort4*>(&dstrow[u * 8]) = lo;
      *reinterpret_cast<ushort4*>(&dstrow[u * 8 + 4]) = hi;
    }
    __syncthreads();
    if (k0 < 480) {
      #pragma unroll
      for (int u = 0; u < 8; u++)
        pf[u] = *reinterpret_cast<const float4*>(&srcrow[k0 + 32 + u * 4]);
    }
    bf16x8 af[4], bfr[4];
    #pragma unroll
    for (int mt = 0; mt < 4; mt++)
      af[mt] = *reinterpret_cast<const bf16x8*>(&As[wr * 64 + mt * 16 + l15][quad * 8]);
    #pragma unroll
    for (int nt = 0; nt < 4; nt++)
      bfr[nt] = *reinterpret_cast<const bf16x8*>(&Bs[wc * 64 + nt * 16 + l15][quad * 8]);
    #pragma unroll
    for (int mt = 0; mt < 4; mt++)
      #pragma unroll
      for (int nt = 0; nt < 4; nt++)
        acc[mt][nt] = __builtin_amdgcn_mfma_f32_16x16x32_bf16(
            af[mt], bfr[nt], acc[mt][nt], 0, 0, 0);
  }

  float bn[4];
  #pragma unroll
  for (int nt = 0; nt < 4; nt++)
    bn[nt] = bias[n0 + wc * 64 + nt * 16 + l15];

  if (z < 2) {
    #pragma unroll
    for (int mt = 0; mt < 4; mt++) {
      #pragma unroll
      for (int r = 0; r < 4; r++) {
        int m = m0 + wr * 64 + mt * 16 + quad * 4 + r;
        int bb = m >> 9, s = m & 511;
        #pragma unroll
        for (int nt = 0; nt < 4; nt++) {
          int n = n0 + wc * 64 + nt * 16 + l15;
          int h = n >> 6, d = n & 63;
          Y[(((size_t)(bb * 8 + h) * 512) + s) * 64 + d] = f2h(acc[mt][nt][r] + bn[nt]);
        }
      }
    }
  } else {
    #pragma unroll
    for (int mt = 0; mt < 4; mt++) {
      #pragma unroll
      for (int r = 0; r < 4; r++) {
        int m = m0 + wr * 64 + mt * 16 + quad * 4 + r;
        int bb = m >> 9, s = m & 511;
        #pragma unroll
        for (int nt = 0; nt < 4; nt++) {
          int n = n0 + wc * 64 + nt * 16 + l15;
          int h = n >> 6, d = n & 63;
          size_t bh = (size_t)(bb * 8 + h);
          Y[(bh * 16 + (s >> 5)) * 2048 + d * 32 + (s & 31)] = f2h(acc[mt][nt][r] + bn[nt]);
        }
      }
    }
  }
}

// ---------------------------------------------------------------------------
// Fused MFMA attention v12 = v11 with the Bkh results routed through the
// per-wave bkhw LDS tile (v10's path) instead of __shfl gather.
// r7 post-mortem: v11's shfl gather kept bk0/bk1 + kheB live across the
// scalar section -> register spill (WRITE_SIZE 16->165 MB, +43 us). Writing
// bk to LDS immediately kills the accumulators' live ranges; the gather
// reverts to 1x ds_read_u16 (same-wave LDS write->read is in-order; each
// quad gathers only rows it wrote). Table fold + XCD remap retained.
// LDS 25,088 B -> 4 blocks/CU. Barrier-free main loop + register binning
// unchanged.
// ---------------------------------------------------------------------------
__global__ __launch_bounds__(256, 4) void attn_mfma(
    const unsigned short* __restrict__ qh16, const unsigned short* __restrict__ kh16,
    const unsigned short* __restrict__ vht,
    const float* __restrict__ qhe, const float* __restrict__ qee,
    const float* __restrict__ khe, const float* __restrict__ kee,
    const float* __restrict__ vhe, const float* __restrict__ vee,
    const unsigned short* __restrict__ de16,
    unsigned short* __restrict__ outp_bf)
{
  const int blk = blockIdx.x;
  const int rt = blk >> 7;
  const int low = blk & 127;
  const int bh = ((low & 15) << 3) | (low >> 4);   // blk%8 == b&7 (bijective)
  const int b = bh >> 3, h = bh & 7;
  const int i0 = rt * 64;
  const int tid = threadIdx.x;
  const int w = tid >> 6;
  const int lane = tid & 63;
  const int l15 = lane & 15, quad = lane >> 4;
  const int bhS = bh * 512;
  const int iL = w * 16 + l15;         // this lane's block-local i-row

  __shared__ union {
    struct {
      float AqF[64][34];               // 8704 B (loop, read-only)
      unsigned short QKes[64][16];     // 2048 B (loop, read-only)
    } a;
    unsigned short embT[64][72];       // 9216 B (epilogue only)
  } U;                                 // 10752 B
  __shared__ unsigned short Pp[4][16][40];    // 5120 B per-wave P tile
  __shared__ unsigned short bkhw[4][32][36];  // 9216 B per-wave Bkh f16 tile
  // total 25,088 B

  const int hoff = h * 64;

  // Q and K fragments for this lane's i-row (bq* reused as Aq A-frags)
  f16x8 bq0 = *reinterpret_cast<const f16x8*>(&qh16[(size_t)(bhS + i0 + iL)*64 + quad*8]);
  f16x8 bq1 = *reinterpret_cast<const f16x8*>(&qh16[(size_t)(bhS + i0 + iL)*64 + 32 + quad*8]);
  f16x8 ak0 = *reinterpret_cast<const f16x8*>(&kh16[(size_t)(bhS + i0 + iL)*64 + quad*8]);
  f16x8 ak1 = *reinterpret_cast<const f16x8*>(&kh16[(size_t)(bhS + i0 + iL)*64 + 32 + quad*8]);

  // emb table B-fragments (f32 -> f16); kheB stays live for the main loop
  f16x8 kheB[2][2];
  #pragma unroll
  for (int nt = 0; nt < 2; nt++)
    #pragma unroll
    for (int kk = 0; kk < 2; kk++)
      kheB[nt][kk] = ldembB(khe, nt * 16 + l15, hoff + kk * 32 + quad * 8);

  // Phase A table MFMAs: Aq[i][t] (2 n-tiles) and QKe[i][e]
  {
    f16x8 qheB[2][2], qeeB[2], keeB[2];
    #pragma unroll
    for (int nt = 0; nt < 2; nt++)
      #pragma unroll
      for (int kk = 0; kk < 2; kk++)
        qheB[nt][kk] = ldembB(qhe, nt * 16 + l15, hoff + kk * 32 + quad * 8);
    #pragma unroll
    for (int kk = 0; kk < 2; kk++) {
      qeeB[kk] = ldembB(qee, l15, hoff + kk * 32 + quad * 8);
      keeB[kk] = ldembB(kee, l15, hoff + kk * 32 + quad * 8);
    }
    f32x4 aacc[2]; f32x4 eacc = (f32x4){0.f,0.f,0.f,0.f};
    #pragma unroll
    for (int nt = 0; nt < 2; nt++) {
      aacc[nt] = (f32x4){0.f,0.f,0.f,0.f};
      aacc[nt] = __builtin_amdgcn_mfma_f32_16x16x32_f16(bq0, qheB[nt][0], aacc[nt], 0, 0, 0);
      aacc[nt] = __builtin_amdgcn_mfma_f32_16x16x32_f16(bq1, qheB[nt][1], aacc[nt], 0, 0, 0);
    }
    eacc = __builtin_amdgcn_mfma_f32_16x16x32_f16(bq0, qeeB[0], eacc, 0, 0, 0);
    eacc = __builtin_amdgcn_mfma_f32_16x16x32_f16(bq1, qeeB[1], eacc, 0, 0, 0);
    eacc = __builtin_amdgcn_mfma_f32_16x16x32_f16(ak0, keeB[0], eacc, 0, 0, 0);
    eacc = __builtin_amdgcn_mfma_f32_16x16x32_f16(ak1, keeB[1], eacc, 0, 0, 0);
    // C layout: row (=i within wave's 16) = quad*4+r, col (=t/e) = l15
    #pragma unroll
    for (int r = 0; r < 4; r++) {
      #pragma unroll
      for (int nt = 0; nt < 2; nt++)
        U.a.AqF[w*16 + quad*4 + r][nt*16 + l15] = aacc[nt][r];
      U.a.QKes[w*16 + quad*4 + r][l15] = f2h(eacc[r]);
    }
  }
  __syncthreads();   // the ONLY pre-loop barrier (AqF/QKes ready)

  const size_t deBase = ((size_t)b*512 + i0 + iL) * 512;  // lane's de16 row

  f32x4 Oacc[4];
  #pragma unroll
  for (int nt = 0; nt < 4; nt++) Oacc[nt] = (f32x4){0.f,0.f,0.f,0.f};
  float sum = 0.f;

  // per-lane register mass bins for row iL (this quad's j-slice)
  float hb[32], eb[16];
  #pragma unroll
  for (int t = 0; t < 32; t++) hb[t] = 0.f;
  #pragma unroll
  for (int t = 0; t < 16; t++) eb[t] = 0.f;

  for (int jc = 0; jc < 16; jc++) {
    const int j0 = jc * 32;

    // per-lane dist/edge (independent global loads; TLP hides latency)
    ushort4 deA = *reinterpret_cast<const ushort4*>(&de16[deBase + j0 + quad*4]);
    ushort4 deB = *reinterpret_cast<const ushort4*>(&de16[deBase + j0 + 16 + quad*4]);

    // QK swapped: C[j = quad*4+r (+tile*16), i = l15]; K frags from global.
    // Bkh for this tile via 4 MFMAs from the same kf0/kf1, routed through
    // per-wave LDS (kills accumulator live ranges -> no spill).
    #pragma unroll
    for (int tile = 0; tile < 2; tile++) {
      const size_t krow = (size_t)(bhS + j0 + tile*16 + l15) * 64;
      f16x8 kf0 = *reinterpret_cast<const f16x8*>(&kh16[krow + quad*8]);
      f16x8 kf1 = *reinterpret_cast<const f16x8*>(&kh16[krow + 32 + quad*8]);
      f32x4 sacc = (f32x4){0.f,0.f,0.f,0.f};
      sacc = __builtin_amdgcn_mfma_f32_16x16x32_f16(kf0, bq0, sacc, 0, 0, 0);
      sacc = __builtin_amdgcn_mfma_f32_16x16x32_f16(kf1, bq1, sacc, 0, 0, 0);
      {
        // bkh[tile*16+quad*4+r][t]: t<16 cols in bk0 (col l15), t>=16 in bk1
        f32x4 bk0 = (f32x4){0.f,0.f,0.f,0.f};
        f32x4 bk1 = (f32x4){0.f,0.f,0.f,0.f};
        bk0 = __builtin_amdgcn_mfma_f32_16x16x32_f16(kf0, kheB[0][0], bk0, 0, 0, 0);
        bk0 = __builtin_amdgcn_mfma_f32_16x16x32_f16(kf1, kheB[0][1], bk0, 0, 0, 0);
        bk1 = __builtin_amdgcn_mfma_f32_16x16x32_f16(kf0, kheB[1][0], bk1, 0, 0, 0);
        bk1 = __builtin_amdgcn_mfma_f32_16x16x32_f16(kf1, kheB[1][1], bk1, 0, 0, 0);
        #pragma unroll
        for (int r = 0; r < 4; r++) {
          bkhw[w][tile*16 + quad*4 + r][l15]      = f2h(bk0[r]);
          bkhw[w][tile*16 + quad*4 + r][16 + l15] = f2h(bk1[r]);
        }
      }
      const int jbase = tile*16 + quad*4;
      const ushort4 de = tile ? deB : deA;
      ushort4 pw;

#define SCALAR_R(rr, ue, pdst)                                                \
      {                                                                       \
        const unsigned u_ = (ue);                                             \
        const int t_ = u_ & 0xFF, e_ = u_ >> 8;                               \
        float bias_ = U.a.AqF[iL][t_] + h2f(bkhw[w][jbase + rr][t_])          \
                    + h2f(U.a.QKes[iL][e_]);                                  \
        float s_ = (sacc[rr] + bias_) * 0.125f;                               \
        float p_ = __expf(fminf(s_, 10.f));                                   \
        sum += p_;                                                            \
        _Pragma("unroll")                                                     \
        for (int t = 0; t < 32; t++) hb[t] += (t == t_) ? p_ : 0.f;           \
        _Pragma("unroll")                                                     \
        for (int t = 0; t < 16; t++) eb[t] += (t == e_) ? p_ : 0.f;           \
        pdst = f2h(p_);                                                       \
      }
      SCALAR_R(0, de.x, pw.x)
      SCALAR_R(1, de.y, pw.y)
      SCALAR_R(2, de.z, pw.z)
      SCALAR_R(3, de.w, pw.w)
#undef SCALAR_R

      // one aligned b64 write: P[i=l15][j = jbase..jbase+3]
      *reinterpret_cast<ushort4*>(&Pp[w][l15][tile*16 + quad*4]) = pw;
    }

    // PV via MFMA (K=32 over this chunk); A = P (wave-private), B = V^T global
    {
      f16x8 ap = *reinterpret_cast<const f16x8*>(&Pp[w][l15][quad*8]);
      const size_t vbase = ((size_t)bh*16 + jc)*2048;
      #pragma unroll
      for (int nt = 0; nt < 4; nt++) {
        f16x8 bv = *reinterpret_cast<const f16x8*>(
            &vht[vbase + (nt*16 + l15)*32 + quad*8]);
        Oacc[nt] = __builtin_amdgcn_mfma_f32_16x16x32_f16(ap, bv, Oacc[nt], 0, 0, 0);
      }
    }
    // NO barrier: everything in this loop is wave-private or read-only.
  }

  // cross-quad reduce: combine the 4 quads' j-slices of row iL.
  sum += __shfl_xor(sum, 16);
  sum += __shfl_xor(sum, 32);
  #pragma unroll
  for (int t = 0; t < 32; t++) {
    hb[t] += __shfl_xor(hb[t], 16);
    hb[t] += __shfl_xor(hb[t], 32);
  }
  #pragma unroll
  for (int t = 0; t < 16; t++) {
    eb[t] += __shfl_xor(eb[t], 16);
    eb[t] += __shfl_xor(eb[t], 32);
  }
  float ri[4];
  #pragma unroll
  for (int r = 0; r < 4; r++) ri[r] = 1.0f / __shfl(sum, quad*4 + r);

  __syncthreads();   // all waves done reading U.a before embT overlays it

  // stage embT [d][k]: k<32 -> vhe, 32..47 -> vee, else 0
  {
    int d = tid & 63, ks0 = (tid >> 6) * 16;
    #pragma unroll
    for (int g = 0; g < 4; g++) {
      ushort4 u;
      #pragma unroll
      for (int kk = 0; kk < 4; kk++) {
        int k = ks0 + g*4 + kk;
        float val = (k < 32) ? vhe[k*512 + h*64 + d]
                  : (k < 48) ? vee[(k-32)*512 + h*64 + d] : 0.f;
        ((unsigned short*)&u)[kk] = f2h(val);
      }
      *reinterpret_cast<ushort4*>(&U.embT[d][ks0 + g*4]) = u;
    }
  }
  __syncthreads();   // embT visible to all waves

  // mass . emb via MFMA; A-frags built from register bins (static selects)
  {
    f16x8 am0, am1;
    #pragma unroll
    for (int j = 0; j < 8; j++) {
      float hv = (quad == 0) ? hb[j]
               : (quad == 1) ? hb[8 + j]
               : (quad == 2) ? hb[16 + j] : hb[24 + j];
      am0[j] = (_Float16)hv;
      float ve = (quad == 0) ? eb[j]
               : (quad == 1) ? eb[8 + j] : 0.f;
      am1[j] = (_Float16)ve;
    }
    #pragma unroll
    for (int nt = 0; nt < 4; nt++) {
      f16x8 be0 = *reinterpret_cast<const f16x8*>(&U.embT[nt*16 + l15][quad*8]);
      f16x8 be1 = *reinterpret_cast<const f16x8*>(&U.embT[nt*16 + l15][32 + quad*8]);
      Oacc[nt] = __builtin_amdgcn_mfma_f32_16x16x32_f16(am0, be0, Oacc[nt], 0, 0, 0);
      Oacc[nt] = __builtin_amdgcn_mfma_f32_16x16x32_f16(am1, be1, Oacc[nt], 0, 0, 0);
    }
  }

  // normalize + store bf16
  #pragma unroll
  for (int nt = 0; nt < 4; nt++) {
    #pragma unroll
    for (int r = 0; r < 4; r++) {
      int srow = i0 + w*16 + quad*4 + r;
      outp_bf[(size_t)(b*512 + srow)*512 + h*64 + nt*16 + l15] = f2bf(Oacc[nt][r] * ri[r]);
    }
  }
}

// ---------------------------------------------------------------------------
// Output proj: X = bf16 (attn output), W = f32 Wo converted in staging.
// ---------------------------------------------------------------------------
__global__ __launch_bounds__(256) void out_mfma(
    const unsigned short* __restrict__ X, const float* __restrict__ Wof,
    const float* __restrict__ bias, float* __restrict__ Y)
{
  __shared__ unsigned short As[128][40];
  __shared__ unsigned short Bs[128][40];
  const int tid = threadIdx.x;
  const int m0 = blockIdx.x * 128;
  const int n0 = blockIdx.y * 128;
  const int lane = tid & 63;
  const int w = tid >> 6;
  const int wr = w >> 1, wc = w & 1;
  const int l15 = lane & 15, quad = lane >> 4;

  const int srow = tid & 127;
  const bool isA = (tid < 128);
  const unsigned short* srcA = &X[(size_t)(m0 + srow) * 512];
  const float* srcB = &Wof[(size_t)(n0 + srow) * 512];
  unsigned short* dstrow = isA ? As[srow] : Bs[srow];

  f32x4 acc[4][4];
  #pragma unroll
  for (int i = 0; i < 4; i++)
    #pragma unroll
    for (int j = 0; j < 4; j++) acc[i][j] = (f32x4){0.f, 0.f, 0.f, 0.f};

  uint4 pa[4]; float4 pb[8];
  if (isA) {
    #pragma unroll
    for (int u = 0; u < 4; u++)
      pa[u] = *reinterpret_cast<const uint4*>(&srcA[u * 8]);
  } else {
    #pragma unroll
    for (int u = 0; u < 8; u++)
      pb[u] = *reinterpret_cast<const float4*>(&srcB[u * 4]);
  }

  for (int k0 = 0; k0 < 512; k0 += 32) {
    __syncthreads();
    if (isA) {
      #pragma unroll
      for (int u = 0; u < 4; u++)
        *reinterpret_cast<uint4*>(&dstrow[u * 8]) = pa[u];
    } else {
      #pragma unroll
      for (int u = 0; u < 4; u++) {
        float4 a = pb[2*u], b2 = pb[2*u + 1];
        ushort4 lo, hi;
        lo.x = f2bf(a.x);  lo.y = f2bf(a.y);  lo.z = f2bf(a.z);  lo.w = f2bf(a.w);
        hi.x = f2bf(b2.x); hi.y = f2bf(b2.y); hi.z = f2bf(b2.z); hi.w = f2bf(b2.w);
        *reinterpret_cast<ushort4*>(&dstrow[u * 8]) = lo;
        *reinterpret_cast<ushort4*>(&dstrow[u * 8 + 4]) = hi;
      }
    }
    __syncthreads();
    if (k0 < 480) {
      if (isA) {
        #pragma unroll
        for (int u = 0; u < 4; u++)
          pa[u] = *reinterpret_cast<const uint4*>(&srcA[k0 + 32 + u * 8]);
      } else {
        #pragma unroll
        for (int u = 0; u < 8; u++)
          pb[u] = *reinterpret_cast<const float4*>(&srcB[k0 + 32 + u * 4]);
      }
    }
    bf16x8 af[4], bfr[4];
    #pragma unroll
    for (int mt = 0; mt < 4; mt++)
      af[mt] = *reinterpret_cast<const bf16x8*>(&As[wr * 64 + mt * 16 + l15][quad * 8]);
    #pragma unroll
    for (int nt = 0; nt < 4; nt++)
      bfr[nt] = *reinterpret_cast<const bf16x8*>(&Bs[wc * 64 + nt * 16 + l15][quad * 8]);
    #pragma unroll
    for (int mt = 0; mt < 4; mt++)
      #pragma unroll
      for (int nt = 0; nt < 4; nt++)
        acc[mt][nt] = __builtin_amdgcn_mfma_f32_16x16x32_bf16(
            af[mt], bfr[nt], acc[mt][nt], 0, 0, 0);
  }

  float bn[4];
  #pragma unroll
  for (int nt = 0; nt < 4; nt++)
    bn[nt] = bias[n0 + wc * 64 + nt * 16 + l15];
  #pragma unroll
  for (int mt = 0; mt < 4; mt++) {
    #pragma unroll
    for (int r = 0; r < 4; r++) {
      int m = m0 + wr * 64 + mt * 16 + quad * 4 + r;
      #pragma unroll
      for (int nt = 0; nt < 4; nt++) {
        int n = n0 + wc * 64 + nt * 16 + l15;
        Y[(size_t)m * 512 + n] = acc[mt][nt][r] + bn[nt];
      }
    }
  }
}

// ---------------------------------------------------------------------------
extern "C" void kernel_launch(void* const* d_in, const int* in_sizes, int n_in,
                              void* d_out, int out_size, void* d_ws, size_t ws_size,
                              hipStream_t stream) {
  (void)in_sizes; (void)n_in; (void)out_size; (void)ws_size;
  const float* q    = (const float*)d_in[0];
  const float* k    = (const float*)d_in[1];
  const float* v    = (const float*)d_in[2];
  const float* qhe  = (const float*)d_in[3];
  const float* qee  = (const float*)d_in[4];
  const float* khe  = (const float*)d_in[5];
  const float* kee  = (const float*)d_in[6];
  const float* vhe  = (const float*)d_in[7];
  const float* vee  = (const float*)d_in[8];
  const int*  dist  = (const int*)d_in[9];
  const int*  edge  = (const int*)d_in[10];
  const float* Wq = (const float*)d_in[11];
  const float* bq = (const float*)d_in[12];
  const float* Wk = (const float*)d_in[13];
  const float* bk = (const float*)d_in[14];
  const float* Wv = (const float*)d_in[15];
  const float* bv = (const float*)d_in[16];
  const float* Wo = (const float*)d_in[17];
  const float* bo = (const float*)d_in[18];

  // ---- workspace layout (bytes) ----
  char* ws = (char*)d_ws;
  unsigned short* qh16  = (unsigned short*)(ws + 0);          // 8,388,608 B
  unsigned short* kh16  = (unsigned short*)(ws + 8388608);    // 8,388,608
  unsigned short* vht   = (unsigned short*)(ws + 16777216);   // 8,388,608
  unsigned short* de16  = (unsigned short*)(ws + 46137344);   // 8,388,608 packed dist|edge
  unsigned short* outp_bf = (unsigned short*)(ws + 71303168); // 8,388,608

  dim3 blk(256);
  hipLaunchKernelGGL(prologue, dim3(1024), blk, 0, stream,
                     q, k, v, Wq, Wk, Wv, bq, bk, bv, qh16, kh16, vht,
                     dist, edge, de16);
  hipLaunchKernelGGL(attn_mfma, dim3(1024), blk, 0, stream,
                     qh16, kh16, vht, qhe, qee, khe, kee, vhe, vee, de16, outp_bf);
  hipLaunchKernelGGL(out_mfma, dim3(64, 4), blk, 0, stream,
                     outp_bf, Wo, bo, (float*)d_out);
}

// Round 9
// 394.181 us; speedup vs baseline: 1.0785x; 1.0618x over previous
//
#include <hip/hip_runtime.h>
#include <hip/hip_fp16.h>

// Problem constants: B=16, S=512, HID=512, NH=8, DK=64, TH=32, TE=16, scale=1/8

typedef __attribute__((ext_vector_type(8))) __bf16 bf16x8;
typedef __attribute__((ext_vector_type(8))) _Float16 f16x8;
typedef __attribute__((ext_vector_type(4))) float f32x4;

static __device__ __forceinline__ unsigned short f2bf(float f) {
  unsigned u = __float_as_uint(f);
  unsigned r = (u + 0x7fffu + ((u >> 16) & 1u)) >> 16;   // RNE
  return (unsigned short)r;
}
static __device__ __forceinline__ unsigned short f2h(float f) {
  _Float16 h = (_Float16)f;
  return __builtin_bit_cast(unsigned short, h);
}
static __device__ __forceinline__ float h2f(unsigned short u) {
  _Float16 h = __builtin_bit_cast(_Float16, u);
  return (float)h;
}
static __device__ __forceinline__ f16x8 ldembB(const float* __restrict__ T,
                                               int row, int off) {
  float4 a = *reinterpret_cast<const float4*>(&T[(size_t)row * 512 + off]);
  float4 b = *reinterpret_cast<const float4*>(&T[(size_t)row * 512 + off + 4]);
  f16x8 r;
  r[0] = (_Float16)a.x; r[1] = (_Float16)a.y; r[2] = (_Float16)a.z; r[3] = (_Float16)a.w;
  r[4] = (_Float16)b.x; r[5] = (_Float16)b.y; r[6] = (_Float16)b.z; r[7] = (_Float16)b.w;
  return r;
}

// ---------------------------------------------------------------------------
// K1 prologue: blocks 0..767 = fused Q/K/V projection GEMMs (f32 in, f16 out,
// f32->bf16 folded into staging, register prefetch); blocks 768..1023 =
// pack dist|edge<<8 into uint16 (grid-stride). One launch, independent parts.
// ---------------------------------------------------------------------------
__global__ __launch_bounds__(256) void prologue(
    const float* __restrict__ qf, const float* __restrict__ kf,
    const float* __restrict__ vf,
    const float* __restrict__ Wq, const float* __restrict__ Wk,
    const float* __restrict__ Wv,
    const float* __restrict__ bq, const float* __restrict__ bk,
    const float* __restrict__ bv,
    unsigned short* __restrict__ qh16, unsigned short* __restrict__ kh16,
    unsigned short* __restrict__ vht,
    const int* __restrict__ dist, const int* __restrict__ edge,
    unsigned short* __restrict__ de16)
{
  __shared__ unsigned short As[128][40];
  __shared__ unsigned short Bs[128][40];
  const int bid = blockIdx.x;
  const int tid = threadIdx.x;

  if (bid >= 768) {                    // ---- pack_de part (memory-bound)
    const int pb = bid - 768;
    #pragma unroll
    for (int rep = 0; rep < 8; rep++) {
      size_t base = ((size_t)(rep * 65536 + pb * 256 + tid)) * 8;
      int4 d0 = *reinterpret_cast<const int4*>(&dist[base]);
      int4 d1 = *reinterpret_cast<const int4*>(&dist[base + 4]);
      int4 e0 = *reinterpret_cast<const int4*>(&edge[base]);
      int4 e1 = *reinterpret_cast<const int4*>(&edge[base + 4]);
      ushort4 u0, u1;
      u0.x = (unsigned short)(d0.x | (e0.x << 8));
      u0.y = (unsigned short)(d0.y | (e0.y << 8));
      u0.z = (unsigned short)(d0.z | (e0.z << 8));
      u0.w = (unsigned short)(d0.w | (e0.w << 8));
      u1.x = (unsigned short)(d1.x | (e1.x << 8));
      u1.y = (unsigned short)(d1.y | (e1.y << 8));
      u1.z = (unsigned short)(d1.z | (e1.z << 8));
      u1.w = (unsigned short)(d1.w | (e1.w << 8));
      *reinterpret_cast<ushort4*>(&de16[base]) = u0;
      *reinterpret_cast<ushort4*>(&de16[base + 4]) = u1;
    }
    return;
  }

  // ---- projection GEMM part
  const int z = bid >> 8;              // 0=q, 1=k, 2=v
  const int xy = bid & 255;
  const int m0 = (xy & 63) * 128;
  const int n0 = (xy >> 6) * 128;
  const float* X = (z == 0) ? qf : (z == 1) ? kf : vf;
  const float* W = (z == 0) ? Wq : (z == 1) ? Wk : Wv;
  const float* bias = (z == 0) ? bq : (z == 1) ? bk : bv;
  unsigned short* Y = (z == 0) ? qh16 : (z == 1) ? kh16 : vht;

  const int lane = tid & 63;
  const int w = tid >> 6;
  const int wr = w >> 1, wc = w & 1;
  const int l15 = lane & 15, quad = lane >> 4;

  const int srow = tid & 127;
  const float* srcrow = (tid < 128) ? &X[(size_t)(m0 + srow) * 512]
                                    : &W[(size_t)(n0 + srow) * 512];
  unsigned short* dstrow = (tid < 128) ? As[srow] : Bs[srow];

  f32x4 acc[4][4];
  #pragma unroll
  for (int i = 0; i < 4; i++)
    #pragma unroll
    for (int j = 0; j < 4; j++) acc[i][j] = (f32x4){0.f, 0.f, 0.f, 0.f};

  float4 pf[8];
  #pragma unroll
  for (int u = 0; u < 8; u++)
    pf[u] = *reinterpret_cast<const float4*>(&srcrow[u * 4]);

  for (int k0 = 0; k0 < 512; k0 += 32) {
    __syncthreads();
    #pragma unroll
    for (int u = 0; u < 4; u++) {
      float4 a = pf[2*u], b2 = pf[2*u + 1];
      ushort4 lo, hi;
      lo.x = f2bf(a.x);  lo.y = f2bf(a.y);  lo.z = f2bf(a.z);  lo.w = f2bf(a.w);
      hi.x = f2bf(b2.x); hi.y = f2bf(b2.y); hi.z = f2bf(b2.z); hi.w = f2bf(b2.w);
      *reinterpret_cast<ushort4*>(&dstrow[u * 8]) = lo;
      *reinterpret_cast<ushort4*>(&dstrow[u * 8 + 4]) = hi;
    }
    __syncthreads();
    if (k0 < 480) {
      #pragma unroll
      for (int u = 0; u < 8; u++)
        pf[u] = *reinterpret_cast<const float4*>(&srcrow[k0 + 32 + u * 4]);
    }
    bf16x8 af[4], bfr[4];
    #pragma unroll
    for (int mt = 0; mt < 4; mt++)
      af[mt] = *reinterpret_cast<const bf16x8*>(&As[wr * 64 + mt * 16 + l15][quad * 8]);
    #pragma unroll
    for (int nt = 0; nt < 4; nt++)
      bfr[nt] = *reinterpret_cast<const bf16x8*>(&Bs[wc * 64 + nt * 16 + l15][quad * 8]);
    #pragma unroll
    for (int mt = 0; mt < 4; mt++)
      #pragma unroll
      for (int nt = 0; nt < 4; nt++)
        acc[mt][nt] = __builtin_amdgcn_mfma_f32_16x16x32_bf16(
            af[mt], bfr[nt], acc[mt][nt], 0, 0, 0);
  }

  float bn[4];
  #pragma unroll
  for (int nt = 0; nt < 4; nt++)
    bn[nt] = bias[n0 + wc * 64 + nt * 16 + l15];

  if (z < 2) {
    #pragma unroll
    for (int mt = 0; mt < 4; mt++) {
      #pragma unroll
      for (int r = 0; r < 4; r++) {
        int m = m0 + wr * 64 + mt * 16 + quad * 4 + r;
        int bb = m >> 9, s = m & 511;
        #pragma unroll
        for (int nt = 0; nt < 4; nt++) {
          int n = n0 + wc * 64 + nt * 16 + l15;
          int h = n >> 6, d = n & 63;
          Y[(((size_t)(bb * 8 + h) * 512) + s) * 64 + d] = f2h(acc[mt][nt][r] + bn[nt]);
        }
      }
    }
  } else {
    #pragma unroll
    for (int mt = 0; mt < 4; mt++) {
      #pragma unroll
      for (int r = 0; r < 4; r++) {
        int m = m0 + wr * 64 + mt * 16 + quad * 4 + r;
        int bb = m >> 9, s = m & 511;
        #pragma unroll
        for (int nt = 0; nt < 4; nt++) {
          int n = n0 + wc * 64 + nt * 16 + l15;
          int h = n >> 6, d = n & 63;
          size_t bh = (size_t)(bb * 8 + h);
          Y[(bh * 16 + (s >> 5)) * 2048 + d * 32 + (s & 31)] = f2h(acc[mt][nt][r] + bn[nt]);
        }
      }
    }
  }
}

// ---------------------------------------------------------------------------
// Bias tables via MFMA. Three tiny GEMMs, K=64:
//   Aq[i][t]   = qh[i,:].qhe[t,:]          (f32 out, 32 cols)
//   Bkh[j][t]  = kh[j,:].khe[t,:]          (f16 out, 32 cols)
//   QKe[i][e]  = qh[i,:].qee[e,:] + kh[i,:].kee[e,:]   (f16 out, 16 cols)
// Operands straight from global (no LDS, no barriers). Block = (bh, quarter),
// 512 blocks x 4 waves; wave handles 32 rows = 2 m-tiles, 24 MFMAs.
// Separate kernel on purpose: folding it into attn spills (r7/r8, WRITE_SIZE
// 103-165 MB of scratch) — attn's register budget is already at the line.
// ---------------------------------------------------------------------------
__global__ __launch_bounds__(256) void table_mfma(
    const unsigned short* __restrict__ qh16, const unsigned short* __restrict__ kh16,
    const float* __restrict__ qhe, const float* __restrict__ qee,
    const float* __restrict__ khe, const float* __restrict__ kee,
    float* __restrict__ Aq, unsigned short* __restrict__ QKe16,
    unsigned short* __restrict__ Bkh16)
{
  const int bh = blockIdx.x >> 2;
  const int part = blockIdx.x & 3;
  const int h = bh & 7;
  const int tid = threadIdx.x;
  const int w = tid >> 6;
  const int lane = tid & 63;
  const int l15 = lane & 15, quad = lane >> 4;
  const int bhS = bh * 512;
  const int ib = part * 128 + w * 32;          // wave's 32 rows
  const int hoff = h * 64;

  // B-fragments from emb tables (loop-invariant, f32 -> f16)
  f16x8 qheB[2][2], kheB[2][2], qeeB[2], keeB[2];
  #pragma unroll
  for (int nt = 0; nt < 2; nt++)
    #pragma unroll
    for (int kk = 0; kk < 2; kk++) {
      qheB[nt][kk] = ldembB(qhe, nt * 16 + l15, hoff + kk * 32 + quad * 8);
      kheB[nt][kk] = ldembB(khe, nt * 16 + l15, hoff + kk * 32 + quad * 8);
    }
  #pragma unroll
  for (int kk = 0; kk < 2; kk++) {
    qeeB[kk] = ldembB(qee, l15, hoff + kk * 32 + quad * 8);
    keeB[kk] = ldembB(kee, l15, hoff + kk * 32 + quad * 8);
  }

  f32x4 aacc[2][2], kacc[2][2], eacc[2];
  #pragma unroll
  for (int mt = 0; mt < 2; mt++) {
    #pragma unroll
    for (int nt = 0; nt < 2; nt++) {
      aacc[mt][nt] = (f32x4){0.f, 0.f, 0.f, 0.f};
      kacc[mt][nt] = (f32x4){0.f, 0.f, 0.f, 0.f};
    }
    eacc[mt] = (f32x4){0.f, 0.f, 0.f, 0.f};
  }

  #pragma unroll
  for (int mt = 0; mt < 2; mt++) {
    #pragma unroll
    for (int kk = 0; kk < 2; kk++) {
      f16x8 aq = *reinterpret_cast<const f16x8*>(
          &qh16[(size_t)(bhS + ib + mt * 16 + l15) * 64 + kk * 32 + quad * 8]);
      f16x8 ak = *reinterpret_cast<const f16x8*>(
          &kh16[(size_t)(bhS + ib + mt * 16 + l15) * 64 + kk * 32 + quad * 8]);
      #pragma unroll
      for (int nt = 0; nt < 2; nt++) {
        aacc[mt][nt] = __builtin_amdgcn_mfma_f32_16x16x32_f16(aq, qheB[nt][kk], aacc[mt][nt], 0, 0, 0);
        kacc[mt][nt] = __builtin_amdgcn_mfma_f32_16x16x32_f16(ak, kheB[nt][kk], kacc[mt][nt], 0, 0, 0);
      }
      eacc[mt] = __builtin_amdgcn_mfma_f32_16x16x32_f16(aq, qeeB[kk], eacc[mt], 0, 0, 0);
      eacc[mt] = __builtin_amdgcn_mfma_f32_16x16x32_f16(ak, keeB[kk], eacc[mt], 0, 0, 0);
    }
  }

  #pragma unroll
  for (int mt = 0; mt < 2; mt++) {
    #pragma unroll
    for (int r = 0; r < 4; r++) {
      int i = ib + mt * 16 + quad * 4 + r;
      size_t base32 = (size_t)(bhS + i) * 32;
      #pragma unroll
      for (int nt = 0; nt < 2; nt++) {
        Aq[base32 + nt * 16 + l15] = aacc[mt][nt][r];
        Bkh16[base32 + nt * 16 + l15] = f2h(kacc[mt][nt][r]);
      }
      QKe16[(size_t)(bhS + i) * 16 + l15] = f2h(eacc[mt][r]);
    }
  }
}

// ---------------------------------------------------------------------------
// Fused MFMA attention v13 = r6's v10 (proven 170.5 us / 16 MB WRITE) + the
// bijective XCD remap from r7 (blk%8 == b&7 -> de16 slab + all tiles of a bh
// share one XCD). The Bkh fold is REVERTED (r7/r8: register spill, 103-165 MB
// scratch traffic). Barrier-free main loop + register binning unchanged.
// ---------------------------------------------------------------------------
__global__ __launch_bounds__(256, 4) void attn_mfma(
    const unsigned short* __restrict__ qh16, const unsigned short* __restrict__ kh16,
    const unsigned short* __restrict__ vht,
    const float* __restrict__ Aq, const unsigned short* __restrict__ QKe16,
    const unsigned short* __restrict__ Bkh16,
    const float* __restrict__ vhe, const float* __restrict__ vee,
    const unsigned short* __restrict__ de16,
    unsigned short* __restrict__ outp_bf)
{
  const int blk = blockIdx.x;
  const int rt = blk >> 7;
  const int low = blk & 127;
  const int bh = ((low & 15) << 3) | (low >> 4);   // blk%8 == b&7 (bijective)
  const int b = bh >> 3, h = bh & 7;
  const int i0 = rt * 64;
  const int tid = threadIdx.x;
  const int w = tid >> 6;
  const int lane = tid & 63;
  const int l15 = lane & 15, quad = lane >> 4;
  const int bhS = bh * 512;
  const int iL = w * 16 + l15;         // this lane's block-local i-row

  __shared__ union {
    struct {
      float AqF[64][34];               // 8704 B (loop, read-only)
      unsigned short QKes[64][16];     // 2048 B (loop, read-only)
    } a;
    unsigned short embT[64][72];       // 9216 B (epilogue only)
  } U;                                 // 10752 B
  __shared__ unsigned short Pp[4][16][40];    // 5120 B per-wave P tile
  __shared__ unsigned short bkhw[4][32][36];  // 9216 B per-wave Bkh f16 copy
  // total 25,088 B

  // ---- Phase A staging (once per block)
  {
    int r = tid >> 2, c = (tid & 3) * 8;   // AqF: 64x32 f32
    float4 a0 = *reinterpret_cast<const float4*>(&Aq[(bhS + i0 + r)*32 + c]);
    float4 a1 = *reinterpret_cast<const float4*>(&Aq[(bhS + i0 + r)*32 + c + 4]);
    *reinterpret_cast<float2*>(&U.a.AqF[r][c])     = make_float2(a0.x, a0.y);
    *reinterpret_cast<float2*>(&U.a.AqF[r][c + 2]) = make_float2(a0.z, a0.w);
    *reinterpret_cast<float2*>(&U.a.AqF[r][c + 4]) = make_float2(a1.x, a1.y);
    *reinterpret_cast<float2*>(&U.a.AqF[r][c + 6]) = make_float2(a1.z, a1.w);
  }
  {
    int r = tid >> 2, t4 = (tid & 3) * 4;  // QKes: 64x16 f16 copy
    ushort4 v4 = *reinterpret_cast<const ushort4*>(&QKe16[(bhS + i0 + r)*16 + t4]);
    *reinterpret_cast<ushort4*>(&U.a.QKes[r][t4]) = v4;
  }

  // Q as MFMA B-fragment (loop-invariant): lane holds Q[i=iL][d=quad*8..]
  f16x8 bq0 = *reinterpret_cast<const f16x8*>(&qh16[(size_t)(bhS + i0 + iL)*64 + quad*8]);
  f16x8 bq1 = *reinterpret_cast<const f16x8*>(&qh16[(size_t)(bhS + i0 + iL)*64 + 32 + quad*8]);
  __syncthreads();   // the ONLY pre-loop barrier (AqF/QKes ready)

  const size_t deBase = ((size_t)b*512 + i0 + iL) * 512;  // lane's de16 row
  // per-lane Bkh staging coords: lane covers row brow, cols bcol..bcol+15
  const int brow = lane >> 1, bcol = (lane & 1) * 16;

  f32x4 Oacc[4];
  #pragma unroll
  for (int nt = 0; nt < 4; nt++) Oacc[nt] = (f32x4){0.f,0.f,0.f,0.f};
  float sum = 0.f;

  // per-lane register mass bins for row iL (this quad's j-slice)
  float hb[32], eb[16];
  #pragma unroll
  for (int t = 0; t < 32; t++) hb[t] = 0.f;
  #pragma unroll
  for (int t = 0; t < 16; t++) eb[t] = 0.f;

  for (int jc = 0; jc < 16; jc++) {
    const int j0 = jc * 32;

    // per-lane dist/edge (independent global loads; TLP hides latency)
    ushort4 deA = *reinterpret_cast<const ushort4*>(&de16[deBase + j0 + quad*4]);
    ushort4 deB = *reinterpret_cast<const ushort4*>(&de16[deBase + j0 + 16 + quad*4]);

    // stage this chunk's Bkh 32x32 f16 into the wave's own LDS copy;
    // wave-in-order LDS pipe orders these writes before the gathers below.
    {
      const unsigned short* src = &Bkh16[(size_t)(bhS + j0 + brow)*32 + bcol];
      #pragma unroll
      for (int g = 0; g < 4; g++) {
        ushort4 u = *reinterpret_cast<const ushort4*>(&src[g*4]);
        *reinterpret_cast<ushort4*>(&bkhw[w][brow][bcol + g*4]) = u;
      }
    }

    // QK swapped: C[j = quad*4+r (+tile*16), i = l15]; K frags from global
    #pragma unroll
    for (int tile = 0; tile < 2; tile++) {
      const size_t krow = (size_t)(bhS + j0 + tile*16 + l15) * 64;
      f16x8 kf0 = *reinterpret_cast<const f16x8*>(&kh16[krow + quad*8]);
      f16x8 kf1 = *reinterpret_cast<const f16x8*>(&kh16[krow + 32 + quad*8]);
      f32x4 sacc = (f32x4){0.f,0.f,0.f,0.f};
      sacc = __builtin_amdgcn_mfma_f32_16x16x32_f16(kf0, bq0, sacc, 0, 0, 0);
      sacc = __builtin_amdgcn_mfma_f32_16x16x32_f16(kf1, bq1, sacc, 0, 0, 0);
      const int jbase = tile*16 + quad*4;
      const ushort4 de = tile ? deB : deA;
      ushort4 pw;

#define SCALAR_R(rr, ue, pdst)                                                \
      {                                                                       \
        const unsigned u_ = (ue);                                             \
        const int t_ = u_ & 0xFF, e_ = u_ >> 8;                               \
        float bias_ = U.a.AqF[iL][t_] + h2f(bkhw[w][jbase + rr][t_])          \
                    + h2f(U.a.QKes[iL][e_]);                                  \
        float s_ = (sacc[rr] + bias_) * 0.125f;                               \
        float p_ = __expf(fminf(s_, 10.f));                                   \
        sum += p_;                                                            \
        _Pragma("unroll")                                                     \
        for (int t = 0; t < 32; t++) hb[t] += (t == t_) ? p_ : 0.f;           \
        _Pragma("unroll")                                                     \
        for (int t = 0; t < 16; t++) eb[t] += (t == e_) ? p_ : 0.f;           \
        pdst = f2h(p_);                                                       \
      }
      SCALAR_R(0, de.x, pw.x)
      SCALAR_R(1, de.y, pw.y)
      SCALAR_R(2, de.z, pw.z)
      SCALAR_R(3, de.w, pw.w)
#undef SCALAR_R

      // one aligned b64 write: P[i=l15][j = jbase..jbase+3]
      *reinterpret_cast<ushort4*>(&Pp[w][l15][jbase]) = pw;
    }

    // PV via MFMA (K=32 over this chunk); A = P (wave-private), B = V^T global
    {
      f16x8 ap = *reinterpret_cast<const f16x8*>(&Pp[w][l15][quad*8]);
      const size_t vbase = ((size_t)bh*16 + jc)*2048;
      #pragma unroll
      for (int nt = 0; nt < 4; nt++) {
        f16x8 bv = *reinterpret_cast<const f16x8*>(
            &vht[vbase + (nt*16 + l15)*32 + quad*8]);
        Oacc[nt] = __builtin_amdgcn_mfma_f32_16x16x32_f16(ap, bv, Oacc[nt], 0, 0, 0);
      }
    }
    // NO barrier: everything in this loop is wave-private or read-only.
  }

  // cross-quad reduce: combine the 4 quads' j-slices of row iL.
  sum += __shfl_xor(sum, 16);
  sum += __shfl_xor(sum, 32);
  #pragma unroll
  for (int t = 0; t < 32; t++) {
    hb[t] += __shfl_xor(hb[t], 16);
    hb[t] += __shfl_xor(hb[t], 32);
  }
  #pragma unroll
  for (int t = 0; t < 16; t++) {
    eb[t] += __shfl_xor(eb[t], 16);
    eb[t] += __shfl_xor(eb[t], 32);
  }
  float ri[4];
  #pragma unroll
  for (int r = 0; r < 4; r++) ri[r] = 1.0f / __shfl(sum, quad*4 + r);

  __syncthreads();   // all waves done reading U.a before embT overlays it

  // stage embT [d][k]: k<32 -> vhe, 32..47 -> vee, else 0
  {
    int d = tid & 63, ks0 = (tid >> 6) * 16;
    #pragma unroll
    for (int g = 0; g < 4; g++) {
      ushort4 u;
      #pragma unroll
      for (int kk = 0; kk < 4; kk++) {
        int k = ks0 + g*4 + kk;
        float val = (k < 32) ? vhe[k*512 + h*64 + d]
                  : (k < 48) ? vee[(k-32)*512 + h*64 + d] : 0.f;
        ((unsigned short*)&u)[kk] = f2h(val);
      }
      *reinterpret_cast<ushort4*>(&U.embT[d][ks0 + g*4]) = u;
    }
  }
  __syncthreads();   // embT visible to all waves

  // mass . emb via MFMA; A-frags built from register bins (static selects)
  {
    f16x8 am0, am1;
    #pragma unroll
    for (int j = 0; j < 8; j++) {
      float hv = (quad == 0) ? hb[j]
               : (quad == 1) ? hb[8 + j]
               : (quad == 2) ? hb[16 + j] : hb[24 + j];
      am0[j] = (_Float16)hv;
      float ve = (quad == 0) ? eb[j]
               : (quad == 1) ? eb[8 + j] : 0.f;
      am1[j] = (_Float16)ve;
    }
    #pragma unroll
    for (int nt = 0; nt < 4; nt++) {
      f16x8 be0 = *reinterpret_cast<const f16x8*>(&U.embT[nt*16 + l15][quad*8]);
      f16x8 be1 = *reinterpret_cast<const f16x8*>(&U.embT[nt*16 + l15][32 + quad*8]);
      Oacc[nt] = __builtin_amdgcn_mfma_f32_16x16x32_f16(am0, be0, Oacc[nt], 0, 0, 0);
      Oacc[nt] = __builtin_amdgcn_mfma_f32_16x16x32_f16(am1, be1, Oacc[nt], 0, 0, 0);
    }
  }

  // normalize + store bf16
  #pragma unroll
  for (int nt = 0; nt < 4; nt++) {
    #pragma unroll
    for (int r = 0; r < 4; r++) {
      int srow = i0 + w*16 + quad*4 + r;
      outp_bf[(size_t)(b*512 + srow)*512 + h*64 + nt*16 + l15] = f2bf(Oacc[nt][r] * ri[r]);
    }
  }
}

// ---------------------------------------------------------------------------
// Output proj: X = bf16 (attn output), W = f32 Wo converted in staging.
// ---------------------------------------------------------------------------
__global__ __launch_bounds__(256) void out_mfma(
    const unsigned short* __restrict__ X, const float* __restrict__ Wof,
    const float* __restrict__ bias, float* __restrict__ Y)
{
  __shared__ unsigned short As[128][40];
  __shared__ unsigned short Bs[128][40];
  const int tid = threadIdx.x;
  const int m0 = blockIdx.x * 128;
  const int n0 = blockIdx.y * 128;
  const int lane = tid & 63;
  const int w = tid >> 6;
  const int wr = w >> 1, wc = w & 1;
  const int l15 = lane & 15, quad = lane >> 4;

  const int srow = tid & 127;
  const bool isA = (tid < 128);
  const unsigned short* srcA = &X[(size_t)(m0 + srow) * 512];
  const float* srcB = &Wof[(size_t)(n0 + srow) * 512];
  unsigned short* dstrow = isA ? As[srow] : Bs[srow];

  f32x4 acc[4][4];
  #pragma unroll
  for (int i = 0; i < 4; i++)
    #pragma unroll
    for (int j = 0; j < 4; j++) acc[i][j] = (f32x4){0.f, 0.f, 0.f, 0.f};

  uint4 pa[4]; float4 pb[8];
  if (isA) {
    #pragma unroll
    for (int u = 0; u < 4; u++)
      pa[u] = *reinterpret_cast<const uint4*>(&srcA[u * 8]);
  } else {
    #pragma unroll
    for (int u = 0; u < 8; u++)
      pb[u] = *reinterpret_cast<const float4*>(&srcB[u * 4]);
  }

  for (int k0 = 0; k0 < 512; k0 += 32) {
    __syncthreads();
    if (isA) {
      #pragma unroll
      for (int u = 0; u < 4; u++)
        *reinterpret_cast<uint4*>(&dstrow[u * 8]) = pa[u];
    } else {
      #pragma unroll
      for (int u = 0; u < 4; u++) {
        float4 a = pb[2*u], b2 = pb[2*u + 1];
        ushort4 lo, hi;
        lo.x = f2bf(a.x);  lo.y = f2bf(a.y);  lo.z = f2bf(a.z);  lo.w = f2bf(a.w);
        hi.x = f2bf(b2.x); hi.y = f2bf(b2.y); hi.z = f2bf(b2.z); hi.w = f2bf(b2.w);
        *reinterpret_cast<ushort4*>(&dstrow[u * 8]) = lo;
        *reinterpret_cast<ushort4*>(&dstrow[u * 8 + 4]) = hi;
      }
    }
    __syncthreads();
    if (k0 < 480) {
      if (isA) {
        #pragma unroll
        for (int u = 0; u < 4; u++)
          pa[u] = *reinterpret_cast<const uint4*>(&srcA[k0 + 32 + u * 8]);
      } else {
        #pragma unroll
        for (int u = 0; u < 8; u++)
          pb[u] = *reinterpret_cast<const float4*>(&srcB[k0 + 32 + u * 4]);
      }
    }
    bf16x8 af[4], bfr[4];
    #pragma unroll
    for (int mt = 0; mt < 4; mt++)
      af[mt] = *reinterpret_cast<const bf16x8*>(&As[wr * 64 + mt * 16 + l15][quad * 8]);
    #pragma unroll
    for (int nt = 0; nt < 4; nt++)
      bfr[nt] = *reinterpret_cast<const bf16x8*>(&Bs[wc * 64 + nt * 16 + l15][quad * 8]);
    #pragma unroll
    for (int mt = 0; mt < 4; mt++)
      #pragma unroll
      for (int nt = 0; nt < 4; nt++)
        acc[mt][nt] = __builtin_amdgcn_mfma_f32_16x16x32_bf16(
            af[mt], bfr[nt], acc[mt][nt], 0, 0, 0);
  }

  float bn[4];
  #pragma unroll
  for (int nt = 0; nt < 4; nt++)
    bn[nt] = bias[n0 + wc * 64 + nt * 16 + l15];
  #pragma unroll
  for (int mt = 0; mt < 4; mt++) {
    #pragma unroll
    for (int r = 0; r < 4; r++) {
      int m = m0 + wr * 64 + mt * 16 + quad * 4 + r;
      #pragma unroll
      for (int nt = 0; nt < 4; nt++) {
        int n = n0 + wc * 64 + nt * 16 + l15;
        Y[(size_t)m * 512 + n] = acc[mt][nt][r] + bn[nt];
      }
    }
  }
}

// ---------------------------------------------------------------------------
extern "C" void kernel_launch(void* const* d_in, const int* in_sizes, int n_in,
                              void* d_out, int out_size, void* d_ws, size_t ws_size,
                              hipStream_t stream) {
  (void)in_sizes; (void)n_in; (void)out_size; (void)ws_size;
  const float* q    = (const float*)d_in[0];
  const float* k    = (const float*)d_in[1];
  const float* v    = (const float*)d_in[2];
  const float* qhe  = (const float*)d_in[3];
  const float* qee  = (const float*)d_in[4];
  const float* khe  = (const float*)d_in[5];
  const float* kee  = (const float*)d_in[6];
  const float* vhe  = (const float*)d_in[7];
  const float* vee  = (const float*)d_in[8];
  const int*  dist  = (const int*)d_in[9];
  const int*  edge  = (const int*)d_in[10];
  const float* Wq = (const float*)d_in[11];
  const float* bq = (const float*)d_in[12];
  const float* Wk = (const float*)d_in[13];
  const float* bk = (const float*)d_in[14];
  const float* Wv = (const float*)d_in[15];
  const float* bv = (const float*)d_in[16];
  const float* Wo = (const float*)d_in[17];
  const float* bo = (const float*)d_in[18];

  // ---- workspace layout (bytes) ----
  char* ws = (char*)d_ws;
  unsigned short* qh16  = (unsigned short*)(ws + 0);          // 8,388,608 B
  unsigned short* kh16  = (unsigned short*)(ws + 8388608);    // 8,388,608
  unsigned short* vht   = (unsigned short*)(ws + 16777216);   // 8,388,608
  float* Aq             = (float*)(ws + 25165824);            // 8,388,608
  unsigned short* Bkh16 = (unsigned short*)(ws + 33554432);   // 4,194,304 used
  unsigned short* QKe16 = (unsigned short*)(ws + 41943040);   // 2,097,152 used
  unsigned short* de16  = (unsigned short*)(ws + 46137344);   // 8,388,608 packed dist|edge
  unsigned short* outp_bf = (unsigned short*)(ws + 71303168); // 8,388,608

  dim3 blk(256);
  hipLaunchKernelGGL(prologue, dim3(1024), blk, 0, stream,
                     q, k, v, Wq, Wk, Wv, bq, bk, bv, qh16, kh16, vht,
                     dist, edge, de16);
  hipLaunchKernelGGL(table_mfma, dim3(512), blk, 0, stream,
                     qh16, kh16, qhe, qee, khe, kee, Aq, QKe16, Bkh16);
  hipLaunchKernelGGL(attn_mfma, dim3(1024), blk, 0, stream,
                     qh16, kh16, vht, Aq, QKe16, Bkh16, vhe, vee, de16, outp_bf);
  hipLaunchKernelGGL(out_mfma, dim3(64, 4), blk, 0, stream,
                     outp_bf, Wo, bo, (float*)d_out);
}